// Round 3
// baseline (726.238 us; speedup 1.0000x reference)
//
#include <hip/hip_runtime.h>

#define HH 512
#define WW 512
#define NB 8
#define TS 16
#define LROW 19              // 18 cols padded to 19 to break bank alignment
#define LPLANE (18*LROW)

typedef unsigned int u32;

// ---------------- threefry2x32 core (verified vs legacy split(PRNGKey(0))) ----------------
__device__ __forceinline__ u32 rotl32(u32 v, int n){ return (v<<n)|(v>>(32-n)); }

struct U2 { u32 x, y; };

__device__ __forceinline__ U2 threefry2x32(u32 k0, u32 k1, u32 x0, u32 x1){
  u32 k2 = k0 ^ k1 ^ 0x1BD11BDAu;
  x0 += k0; x1 += k1;
  const int RA[4] = {13,15,26,6};
  const int RB[4] = {17,29,16,24};
  #pragma unroll
  for(int i=0;i<4;i++){ x0+=x1; x1=rotl32(x1,RA[i]); x1^=x0; }
  x0 += k1; x1 += k2 + 1u;
  #pragma unroll
  for(int i=0;i<4;i++){ x0+=x1; x1=rotl32(x1,RB[i]); x1^=x0; }
  x0 += k2; x1 += k0 + 2u;
  #pragma unroll
  for(int i=0;i<4;i++){ x0+=x1; x1=rotl32(x1,RA[i]); x1^=x0; }
  x0 += k0; x1 += k1 + 3u;
  #pragma unroll
  for(int i=0;i<4;i++){ x0+=x1; x1=rotl32(x1,RB[i]); x1^=x0; }
  x0 += k1; x1 += k2 + 4u;
  #pragma unroll
  for(int i=0;i<4;i++){ x0+=x1; x1=rotl32(x1,RA[i]); x1^=x0; }
  x0 += k2; x1 += k0 + 5u;
  U2 r; r.x = x0; r.y = x1; return r;
}

// ---- partitionable (modern JAX default) 32-bit draw: element i of a <2^32 draw ----
// counter = (hi32(i)=0, lo32(i)=i); output = x ^ y
__device__ __forceinline__ u32 pbits(u32 k0, u32 k1, u32 i){
  U2 o = threefry2x32(k0, k1, 0u, i);
  return o.x ^ o.y;
}

// XLA/Eigen f32 erf_inv (Giles polynomial)
__device__ __forceinline__ float xla_erfinv(float x){
  float w = -log1pf(-x*x);
  float p;
  if (w < 5.0f){
    w -= 2.5f;
    p = 2.81022636e-08f;
    p = fmaf(p,w, 3.43273939e-07f);
    p = fmaf(p,w,-3.5233877e-06f);
    p = fmaf(p,w,-4.39150654e-06f);
    p = fmaf(p,w, 0.00021858087f);
    p = fmaf(p,w,-0.00125372503f);
    p = fmaf(p,w,-0.00417768164f);
    p = fmaf(p,w, 0.246640727f);
    p = fmaf(p,w, 1.50140941f);
  } else {
    w = sqrtf(w) - 3.0f;
    p = -0.000200214257f;
    p = fmaf(p,w, 0.000100950558f);
    p = fmaf(p,w, 0.00134934322f);
    p = fmaf(p,w,-0.00367342844f);
    p = fmaf(p,w, 0.00573950773f);
    p = fmaf(p,w,-0.0076224613f);
    p = fmaf(p,w, 0.00943887047f);
    p = fmaf(p,w, 1.00167406f);
    p = fmaf(p,w, 2.83297682f);
  }
  return p*x;
}

__device__ __forceinline__ float normal_from_bits(u32 bits){
  const float LO = -0.99999994f;          // nextafterf(-1,0)
  u32 fb = (bits >> 9) | 0x3F800000u;
  float f = __uint_as_float(fb) - 1.0f;   // [0,1)
  float u = f * 2.0f + LO;                // (maxval-minval) rounds to 2.0f exactly
  u = fmaxf(LO, u);
  return 1.41421356f * xla_erfinv(u);
}

// foldlike split (partitionable): child i = threefry(key, (0, i)) full block
__device__ __forceinline__ void noise_keys(int seed, u32& k1a, u32& k1b, u32& k2a, u32& k2b){
  u32 K0 = 0u;                             // JAX threefry_seed: logical >>32 of int32 -> 0
  u32 K1 = (u32)seed;
  U2 nk = threefry2x32(K0, K1, 0u, 1u);    // key,nk = split(key): nk = child 1
  U2 c1 = threefry2x32(nk.x, nk.y, 0u, 0u);// k1,k2 = split(nk)
  U2 c2 = threefry2x32(nk.x, nk.y, 0u, 1u);
  k1a = c1.x; k1b = c1.y;                  // k1 (vx noise)
  k2a = c2.x; k2b = c2.y;                  // k2 (vy noise)
}

// ---------------- kernel A: perception + MLP + mask ----------------
__global__ __launch_bounds__(256) void nca_main(
    const float* __restrict__ st, const int* __restrict__ seedp,
    const float* __restrict__ w1, const float* __restrict__ b1,
    const float* __restrict__ w2, const float* __restrict__ b2,
    const float* __restrict__ w_rgb, const float* __restrict__ b_rgb,
    const float* __restrict__ w_vel, const float* __restrict__ b_vel,
    const float* __restrict__ w_hid, const float* __restrict__ b_hid,
    float* __restrict__ out)
{
  __shared__ float ls[16][LPLANE];   // channel-major halo tile, ~21.9 KB
  const int tid = threadIdx.x;
  const int bx = blockIdx.x, by = blockIdx.y, b = blockIdx.z;
  const int x0t = bx*TS, y0t = by*TS;
  const float* __restrict__ sb = st + (size_t)b*HH*WW*16;

  // stage 18x18 pixels x 16ch, torus wrap via &511
  for (int t = tid; t < 18*18*4; t += 256){
    int pix = t >> 2, part = t & 3;
    int py = pix / 18, px = pix - py*18;
    int gy = (y0t + py - 1) & (HH-1);
    int gx = (x0t + px - 1) & (WW-1);
    const float4 v = *(const float4*)(sb + ((gy*WW + gx)*16 + part*4));
    int li = py*LROW + px;
    ls[part*4+0][li] = v.x; ls[part*4+1][li] = v.y;
    ls[part*4+2][li] = v.z; ls[part*4+3][li] = v.w;
  }
  __syncthreads();

  const int lx = tid & 15, ly = tid >> 4;
  const int ygl = y0t + ly, xgl = x0t + lx;
  const int ctr = (ly+1)*LROW + (lx+1);

  // ---- layer 1: x1 = relu(p @ w1 + b1), perception on the fly ----
  float x1[64];
  #pragma unroll
  for (int d = 0; d < 64; ++d) x1[d] = b1[d];

  for (int c = 0; c < 16; ++c){                      // identity
    float pc = ls[c][ctr];
    const float* __restrict__ wr = w1 + c*64;
    #pragma unroll
    for (int d = 0; d < 64; ++d) x1[d] = fmaf(pc, wr[d], x1[d]);
  }
  for (int c = 0; c < 16; ++c){                      // sobel x
    const float* __restrict__ pl = ls[c];
    float pc = (pl[ctr-LROW+1] + 2.0f*pl[ctr+1] + pl[ctr+LROW+1]
              - pl[ctr-LROW-1] - 2.0f*pl[ctr-1] - pl[ctr+LROW-1]) * 0.125f;
    const float* __restrict__ wr = w1 + (16+c)*64;
    #pragma unroll
    for (int d = 0; d < 64; ++d) x1[d] = fmaf(pc, wr[d], x1[d]);
  }
  for (int c = 0; c < 16; ++c){                      // sobel y
    const float* __restrict__ pl = ls[c];
    float pc = (pl[ctr+LROW-1] + 2.0f*pl[ctr+LROW] + pl[ctr+LROW+1]
              - pl[ctr-LROW-1] - 2.0f*pl[ctr-LROW] - pl[ctr-LROW+1]) * 0.125f;
    const float* __restrict__ wr = w1 + (32+c)*64;
    #pragma unroll
    for (int d = 0; d < 64; ++d) x1[d] = fmaf(pc, wr[d], x1[d]);
  }
  for (int c = 0; c < 16; ++c){                      // laplacian
    const float* __restrict__ pl = ls[c];
    float pc = (pl[ctr+1] + pl[ctr-1] + pl[ctr+LROW] + pl[ctr-LROW]
              - 4.0f*pl[ctr]) * 0.25f;
    const float* __restrict__ wr = w1 + (48+c)*64;
    #pragma unroll
    for (int d = 0; d < 64; ++d) x1[d] = fmaf(pc, wr[d], x1[d]);
  }
  #pragma unroll
  for (int d = 0; d < 64; ++d) x1[d] = fmaxf(x1[d], 0.0f);

  // ---- layer 2 ----
  float x2[32];
  #pragma unroll
  for (int d = 0; d < 32; ++d) x2[d] = b2[d];
  for (int c = 0; c < 64; ++c){
    float xc = x1[c];
    const float* __restrict__ wr = w2 + c*32;
    #pragma unroll
    for (int d = 0; d < 32; ++d) x2[d] = fmaf(xc, wr[d], x2[d]);
  }
  #pragma unroll
  for (int d = 0; d < 32; ++d) x2[d] = fmaxf(x2[d], 0.0f);

  // ---- heads ----
  float rgb[3], vel[2], hid[8];
  #pragma unroll
  for (int j = 0; j < 3; ++j) rgb[j] = b_rgb[j];
  #pragma unroll
  for (int j = 0; j < 2; ++j) vel[j] = b_vel[j];
  #pragma unroll
  for (int j = 0; j < 8; ++j) hid[j] = b_hid[j];
  for (int c = 0; c < 32; ++c){
    float xc = x2[c];
    #pragma unroll
    for (int j = 0; j < 3; ++j) rgb[j] = fmaf(xc, w_rgb[c*3+j], rgb[j]);
    #pragma unroll
    for (int j = 0; j < 2; ++j) vel[j] = fmaf(xc, w_vel[c*2+j], vel[j]);
    #pragma unroll
    for (int j = 0; j < 8; ++j) hid[j] = fmaf(xc, w_hid[c*8+j], hid[j]);
  }

  // ---- mask: partitionable bernoulli on the ORIGINAL key ----
  int seed = seedp[0];
  u32 K0 = 0u;
  u32 K1 = (u32)seed;
  const u32 pix = ((u32)b*HH + ygl)*WW + xgl;
  u32 mbits = pbits(K0, K1, pix);
  float m = ((int)mbits >= 0) ? 1.0f : 0.0f;   // u < 0.5 <=> top bit clear

  // ---- assemble new state ----
  float sc[16];
  #pragma unroll
  for (int ch = 0; ch < 16; ++ch) sc[ch] = ls[ch][ctr];

  float ds[16];
  ds[0]=rgb[0]; ds[1]=rgb[1]; ds[2]=rgb[2];
  ds[3]=0.0f;
  ds[4]=vel[0]; ds[5]=vel[1];
  ds[6]=0.0f; ds[7]=0.0f;
  #pragma unroll
  for (int j = 0; j < 8; ++j) ds[8+j] = hid[j];

  float ns[16];
  #pragma unroll
  for (int ch = 0; ch < 16; ++ch) ns[ch] = sc[ch] + ds[ch]*m;

  ns[4] = 0.95f * fminf(fmaxf(ns[4], -1.0f), 1.0f);
  ns[5] = 0.95f * fminf(fmaxf(ns[5], -1.0f), 1.0f);
  ns[0] = fminf(fmaxf(ns[0], 0.0f), 1.0f);
  ns[1] = fminf(fmaxf(ns[1], 0.0f), 1.0f);
  ns[2] = fminf(fmaxf(ns[2], 0.0f), 1.0f);
  ns[3] = sc[3];   // mass placeholder (kernel D overwrites)

  float* __restrict__ op = out + (size_t)pix*16;
  *(float4*)(op+ 0) = make_float4(ns[0],ns[1],ns[2],ns[3]);
  *(float4*)(op+ 4) = make_float4(ns[4],ns[5],ns[6],ns[7]);
  *(float4*)(op+ 8) = make_float4(ns[8],ns[9],ns[10],ns[11]);
  *(float4*)(op+12) = make_float4(ns[12],ns[13],ns[14],ns[15]);
}

// ---------------- advection helpers ----------------
__device__ __forceinline__ float bilin_strided(const float* __restrict__ mp, int stride, int off,
                                               float yy, float xx, float vx, float vy){
  float sy = yy - vy*0.25f;
  float sx = xx - vx*0.25f;
  float y0f = floorf(sy), x0f = floorf(sx);
  float fy = sy - y0f,   fx = sx - x0f;
  int y0 = ((int)y0f) & 511, x0 = ((int)x0f) & 511;
  int y1 = (y0+1) & 511,     x1 = (x0+1) & 511;
  float m00 = mp[((y0<<9)+x0)*stride+off], m01 = mp[((y0<<9)+x1)*stride+off];
  float m10 = mp[((y1<<9)+x0)*stride+off], m11 = mp[((y1<<9)+x1)*stride+off];
  return (1.0f-fy)*((1.0f-fx)*m00 + fx*m01) + fy*((1.0f-fx)*m10 + fx*m11);
}

// kernel B: m1 = advect(state_mass)   (mass read from input state ch3)
__global__ __launch_bounds__(256) void advect_step1(
    const float* __restrict__ st, const float* __restrict__ out,
    const int* __restrict__ seedp, float* __restrict__ m1)
{
  int i = blockIdx.x*256 + threadIdx.x;
  int b = i >> 18; int rem = i & 0x3FFFF; int y = rem >> 9; int x = rem & 511;
  u32 k1a,k1b,k2a,k2b; noise_keys(seedp[0], k1a,k1b,k2a,k2b);
  float vx = out[(size_t)i*16+4] + 0.2f*normal_from_bits(pbits(k1a,k1b,(u32)i));
  float vy = out[(size_t)i*16+5] + 0.2f*normal_from_bits(pbits(k2a,k2b,(u32)i));
  const float* mb = st + (((size_t)b)<<18)*16;
  m1[i] = bilin_strided(mb, 16, 3, (float)y, (float)x, vx, vy);
}

// kernel C: m2 = advect(m1)
__global__ __launch_bounds__(256) void advect_step2(
    const float* __restrict__ m1, const float* __restrict__ out,
    const int* __restrict__ seedp, float* __restrict__ m2)
{
  int i = blockIdx.x*256 + threadIdx.x;
  int b = i >> 18; int rem = i & 0x3FFFF; int y = rem >> 9; int x = rem & 511;
  u32 k1a,k1b,k2a,k2b; noise_keys(seedp[0], k1a,k1b,k2a,k2b);
  float vx = out[(size_t)i*16+4] + 0.2f*normal_from_bits(pbits(k1a,k1b,(u32)i));
  float vy = out[(size_t)i*16+5] + 0.2f*normal_from_bits(pbits(k2a,k2b,(u32)i));
  const float* mb = m1 + (((size_t)b)<<18);
  m2[i] = bilin_strided(mb, 1, 0, (float)y, (float)x, vx, vy);
}

// kernel D: diffusion on m2 -> out ch3
__global__ __launch_bounds__(256) void diffuse_k(
    const float* __restrict__ m2, float* __restrict__ out)
{
  int i = blockIdx.x*256 + threadIdx.x;
  int b = i >> 18; int rem = i & 0x3FFFF; int y = rem >> 9; int x = rem & 511;
  const float* mb = m2 + (((size_t)b)<<18);
  float c = mb[(y<<9)+x];
  float r = mb[(y<<9)+((x+1)&511)];
  float l = mb[(y<<9)+((x-1)&511)];
  float d = mb[(((y+1)&511)<<9)+x];
  float u = mb[(((y-1)&511)<<9)+x];
  out[(size_t)i*16 + 3] = c + 0.05f*((r+l+d+u)*0.25f - c);
}

// ---------------- launch ----------------
extern "C" void kernel_launch(void* const* d_in, const int* in_sizes, int n_in,
                              void* d_out, int out_size, void* d_ws, size_t ws_size,
                              hipStream_t stream)
{
  const float* st   = (const float*)d_in[0];
  const int*   seed = (const int*)  d_in[1];
  const float* w1   = (const float*)d_in[2];
  const float* b1   = (const float*)d_in[3];
  const float* w2   = (const float*)d_in[4];
  const float* b2   = (const float*)d_in[5];
  const float* wrgb = (const float*)d_in[6];
  const float* brgb = (const float*)d_in[7];
  const float* wvel = (const float*)d_in[8];
  const float* bvel = (const float*)d_in[9];
  const float* whid = (const float*)d_in[10];
  const float* bhid = (const float*)d_in[11];
  float* out = (float*)d_out;

  const int npix = NB*HH*WW;            // 2^21
  float* m1p = (float*)d_ws;            // 2 planes x 8 MB = 16 MB scratch
  float* m2p = m1p + npix;

  dim3 gridA(WW/TS, HH/TS, NB);
  nca_main<<<gridA, 256, 0, stream>>>(st, seed, w1,b1,w2,b2,wrgb,brgb,wvel,bvel,whid,bhid, out);
  advect_step1<<<npix/256, 256, 0, stream>>>(st, out, seed, m1p);
  advect_step2<<<npix/256, 256, 0, stream>>>(m1p, out, seed, m2p);
  diffuse_k<<<npix/256, 256, 0, stream>>>(m2p, out);
}